// Round 8
// baseline (236.490 us; speedup 1.0000x reference)
//
#include <hip/hip_runtime.h>
#include <hip/hip_bf16.h>
#include <math.h>

#define B_    4
#define N_    4096
#define DIM_  256
#define H_    8
#define DH_   64
#define P_    2
#define INNER_ 512
#define BN_   (B_ * N_)      // 16384 rows for q/out
#define KVR_  (2 * BN_)      // 32768 rows for k/v
#define VOFF_ ((size_t)H_ * KVR_ * DH_)   // shorts offset of V block in khv

typedef short v8s  __attribute__((ext_vector_type(8)));
typedef short v4s  __attribute__((ext_vector_type(4)));
typedef float v4f  __attribute__((ext_vector_type(4)));

__device__ __forceinline__ short f2b(float x) {
    __hip_bfloat16 h = __float2bfloat16(x);
    return *reinterpret_cast<short*>(&h);
}
__device__ __forceinline__ float b2f(short s) {
    __hip_bfloat16 h = *reinterpret_cast<__hip_bfloat16*>(&s);
    return __bfloat162float(h);
}

__device__ __forceinline__ void async16(const void* g, void* l) {
    __builtin_amdgcn_global_load_lds(
        (const __attribute__((address_space(1))) void*)g,
        (__attribute__((address_space(3))) void*)l, 16, 0, 0);
}

__device__ __forceinline__ void storeRow(float* p, float4 f0, float4 f1, float4 f2, float4 f3) {
    ((float4*)p)[0] = f0; ((float4*)p)[1] = f1; ((float4*)p)[2] = f2; ((float4*)p)[3] = f3;
}
__device__ __forceinline__ void storeRowS(short* p, float4 f0, float4 f1, float4 f2, float4 f3) {
    v8s o0, o1;
    o0[0]=f2b(f0.x); o0[1]=f2b(f0.y); o0[2]=f2b(f0.z); o0[3]=f2b(f0.w);
    o0[4]=f2b(f1.x); o0[5]=f2b(f1.y); o0[6]=f2b(f1.z); o0[7]=f2b(f1.w);
    o1[0]=f2b(f2.x); o1[1]=f2b(f2.y); o1[2]=f2b(f2.z); o1[3]=f2b(f2.w);
    o1[4]=f2b(f3.x); o1[5]=f2b(f3.y); o1[6]=f2b(f3.z); o1[7]=f2b(f3.w);
    ((v8s*)p)[0] = o0; ((v8s*)p)[1] = o1;
}

// ---------------------------------------------------------------------------
// MERGED weight prep, one dispatch.
// R8: branch-1 (Wq2t/Wkvt) now emits B in MFMA-FRAGMENT-PANEL order:
//   panel(jt = n>>4, T = k>>6): elem idx =
//     ((jt*NT + T)*8 + chunk)*128 + (n&15)*8 + (k&7),  chunk = (k>>3)&7
// so a gemm wave's bF[j][ks] load (lane = g*16+lm) reads CONSECUTIVE 16B
// per lane -> coalesced 1KB/instruction direct from L2 (fixes R5's
// lane-major failure). Woutb (branch-3) unchanged (gemm_out keeps LDS path).
// ---------------------------------------------------------------------------
__global__ __launch_bounds__(256) void prep_all(
    const float* __restrict__ Wq, const float* __restrict__ gq, const float* __restrict__ betaq,
    const float* __restrict__ Wk, const float* __restrict__ gk, const float* __restrict__ betak,
    const float* __restrict__ bk,
    const float* __restrict__ Wv, const float* __restrict__ gv, const float* __restrict__ betav,
    const float* __restrict__ bv,
    const float* __restrict__ Woff, const float* __restrict__ Wout,
    short* __restrict__ Wq2t, float* __restrict__ bq2,
    short* __restrict__ Wkvt, float* __restrict__ bkv,
    float* __restrict__ Wcomb, float* __restrict__ braw, short* __restrict__ Woutb) {
    __shared__ float sm[272];
    const int bid = blockIdx.x, t = threadIdx.x;

    if (bid < 1536) {
        const float *W, *g, *beta, *bias_in;
        short* Wt; float* b2; int K, n, ng; float scale;
        if (bid < 512)       { W=Wq; g=gq; beta=betaq; bias_in=nullptr; Wt=Wq2t; b2=bq2; K=512; n=bid;       ng=n;          scale=0.125f; }
        else if (bid < 1024) { W=Wk; g=gk; beta=betak; bias_in=bk; Wt=Wkvt; b2=bkv;       K=256; n=bid-512;  ng=n;          scale=1.f; }
        else                 { W=Wv; g=gv; beta=betav; bias_in=bv; Wt=Wkvt; b2=bkv+512;   K=256; n=bid-1024; ng=n+512;      scale=1.f; }
        const int NT = K >> 6;
        const int jt = ng >> 4, lmn = ng & 15;
        float partial = 0.f;
        for (int k = t; k < K; k += 256) {
            float w = W[k * 512 + n];
            const int T = k >> 6, chunk = (k >> 3) & 7, e = k & 7;
            Wt[(size_t)(((jt * NT + T) * 8 + chunk) * 128 + lmn * 8 + e)] = f2b(scale * g[k] * w);
            partial += beta[k] * w;
        }
        sm[t] = partial;
        __syncthreads();
        for (int s = 128; s > 0; s >>= 1) {
            if (t < s) sm[t] += sm[t + s];
            __syncthreads();
        }
        if (t == 0) b2[n] = scale * ((bias_in ? bias_in[n] : 0.f) + sm[0]);
    } else if (bid < 2048) {
        const int k = bid - 1536;
        const int hp = t & 15, jg = t >> 4;
        float p = 0.f;
        for (int j = jg; j < INNER_; j += 16)
            p += Wq[k * INNER_ + j] * Woff[hp * INNER_ + j];
        sm[jg * 17 + hp] = p;
        __syncthreads();
        if (t < 16) {
            float s = 0.f;
            for (int i = 0; i < 16; i++) s += sm[i * 17 + t];
            Wcomb[k * 16 + t] = gq[k] * s;
            braw[k * 16 + t]  = betaq[k] * s;
        }
    } else {
        const int i0 = (bid - 2048) * 1024 + t * 4;
        float4 f = *(const float4*)(Wout + i0);
        v4s o;
        o[0] = f2b(f.x); o[1] = f2b(f.y); o[2] = f2b(f.z); o[3] = f2b(f.w);
        *(v4s*)(Woutb + i0) = o;
    }
}

// ---------------------------------------------------------------------------
// FUSED single-pass LN + activations + offsets. One wave per 4 rows.
// R8: bcomb finalize sync deferred to just before the final reduce.
// ---------------------------------------------------------------------------
__global__ __launch_bounds__(256) void norm_fused_kernel(
    const float* __restrict__ x, const float* __restrict__ p,
    const float* __restrict__ Wcomb, const float* __restrict__ braw,
    const float* __restrict__ boff,
    short* __restrict__ Aq, short* __restrict__ Akv,
    float* __restrict__ out_off, int* __restrict__ idx) {
    __shared__ float smr[272];
    __shared__ float sc[4][4][16][33];   // [wave][row][out j][lane<32] (+pad)
    const int t    = threadIdx.x;
    const int lane = t & 63;
    const int wv   = t >> 6;
    const int m0   = (blockIdx.x * 4 + wv) * 4;   // first of 4 rows
    const int k8   = lane * 8;

    // per-block bcomb partials (braw is L2-hot, 32KB)
    {
        const int hp = t & 15, kg = t >> 4;
        float pp = 0.f;
        for (int k = kg; k < 512; k += 16) pp += braw[k * 16 + hp];
        smr[kg * 17 + hp] = pp;
    }
    __syncthreads();
    if (t < 16) {
        float s = 0.f;
#pragma unroll
        for (int i = 0; i < 16; i++) s += smr[i * 17 + t];
        smr[256 + t] = s + boff[t];
    }
    // NOTE: finalize sync deferred to just before the final reduce.

    float4 w[8][4];
#pragma unroll
    for (int i = 0; i < 8; i++) {
        const float4* wr = (const float4*)(Wcomb + (size_t)(k8 + i) * 16);
#pragma unroll
        for (int j = 0; j < 4; j++) w[i][j] = wr[j];
    }

    const float* srcb = (lane < 32) ? (x + k8) : (p + k8 - DIM_);

    // load all 4 rows up front (independent)
    float4 ua[4][2];
#pragma unroll
    for (int r = 0; r < 4; r++) {
        ua[r][0] = ((const float4*)(srcb + (size_t)(m0 + r) * DIM_))[0];
        ua[r][1] = ((const float4*)(srcb + (size_t)(m0 + r) * DIM_))[1];
    }

    // interleaved stats: 4 independent shuffle chains
    float s[4], q2[4];
#pragma unroll
    for (int r = 0; r < 4; r++) {
        float uv[8] = { ua[r][0].x, ua[r][0].y, ua[r][0].z, ua[r][0].w,
                        ua[r][1].x, ua[r][1].y, ua[r][1].z, ua[r][1].w };
        float ss = 0.f, qq = 0.f;
#pragma unroll
        for (int i = 0; i < 8; i++) { ss += uv[i]; qq += uv[i] * uv[i]; }
        s[r] = ss; q2[r] = qq;
    }
#pragma unroll
    for (int d = 1; d <= 16; d <<= 1) {
#pragma unroll
        for (int r = 0; r < 4; r++) {
            s[r]  += __shfl_xor(s[r], d);
            q2[r] += __shfl_xor(q2[r], d);
        }
    }
    float mean_h[4], rstd_h[4], mean_q[4], rstd_q[4];
#pragma unroll
    for (int r = 0; r < 4; r++) {
        mean_h[r] = s[r] * (1.f / 256.f);
        float var_h = q2[r] * (1.f / 256.f) - mean_h[r] * mean_h[r];
        rstd_h[r] = rsqrtf(var_h + 1e-5f);
        float sf  = s[r]  + __shfl_xor(s[r], 32);
        float q2f = q2[r] + __shfl_xor(q2[r], 32);
        mean_q[r] = sf * (1.f / 512.f);
        float var_q = q2f * (1.f / 512.f) - mean_q[r] * mean_q[r];
        rstd_q[r] = rsqrtf(var_q + 1e-5f);
    }

    // per-row: normalize, store activations, partial offset dot
#pragma unroll
    for (int r = 0; r < 4; r++) {
        const int m = m0 + r;
        float uv[8] = { ua[r][0].x, ua[r][0].y, ua[r][0].z, ua[r][0].w,
                        ua[r][1].x, ua[r][1].y, ua[r][1].z, ua[r][1].w };

        v8s okv;
#pragma unroll
        for (int i = 0; i < 8; i++) okv[i] = f2b((uv[i] - mean_h[r]) * rstd_h[r]);
        short* akvdst = Akv + ((lane < 32) ? ((size_t)m * DIM_ + k8)
                                           : ((size_t)(BN_ + m) * DIM_ + k8 - DIM_));
        *(v8s*)akvdst = okv;

        float nv[8];
        v8s oq;
#pragma unroll
        for (int i = 0; i < 8; i++) { nv[i] = (uv[i] - mean_q[r]) * rstd_q[r]; oq[i] = f2b(nv[i]); }
        *(v8s*)(Aq + (size_t)m * INNER_ + k8) = oq;

        float acc[16];
#pragma unroll
        for (int h = 0; h < 16; h++) acc[h] = 0.f;
#pragma unroll
        for (int i = 0; i < 8; i++) {
            float nvi = nv[i];
            acc[0]  += nvi * w[i][0].x;  acc[1]  += nvi * w[i][0].y;
            acc[2]  += nvi * w[i][0].z;  acc[3]  += nvi * w[i][0].w;
            acc[4]  += nvi * w[i][1].x;  acc[5]  += nvi * w[i][1].y;
            acc[6]  += nvi * w[i][1].z;  acc[7]  += nvi * w[i][1].w;
            acc[8]  += nvi * w[i][2].x;  acc[9]  += nvi * w[i][2].y;
            acc[10] += nvi * w[i][2].z;  acc[11] += nvi * w[i][2].w;
            acc[12] += nvi * w[i][3].x;  acc[13] += nvi * w[i][3].y;
            acc[14] += nvi * w[i][3].z;  acc[15] += nvi * w[i][3].w;
        }
        // fold lane <-> lane+32 (depth-1), park partials in LDS
#pragma unroll
        for (int j = 0; j < 16; j++) acc[j] += __shfl_xor(acc[j], 32);
        if (lane < 32) {
#pragma unroll
            for (int j = 0; j < 16; j++) sc[wv][r][j][lane] = acc[j];
        }
    }
    asm volatile("s_waitcnt lgkmcnt(0)" ::: "memory");   // wave-local LDS visible
    __syncthreads();   // smr[256+] finalized (deferred sync)

    // final reduce: all 64 lanes, lane = r*16 + j
    {
        const int r3 = lane >> 4, j3 = lane & 15;
        const float* sp = &sc[wv][r3][j3][0];
        float4 p0 = *(const float4*)(sp + 0),  p1 = *(const float4*)(sp + 4);
        float4 p2 = *(const float4*)(sp + 8),  p3 = *(const float4*)(sp + 12);
        float4 p4 = *(const float4*)(sp + 16), p5 = *(const float4*)(sp + 20);
        float4 p6 = *(const float4*)(sp + 24), p7 = *(const float4*)(sp + 28);
        float sx = ((p0.x + p1.x) + (p2.x + p3.x)) + ((p4.x + p5.x) + (p6.x + p7.x));
        float sy = ((p0.y + p1.y) + (p2.y + p3.y)) + ((p4.y + p5.y) + (p6.y + p7.y));
        float sz = ((p0.z + p1.z) + (p2.z + p3.z)) + ((p4.z + p5.z) + (p6.z + p7.z));
        float sw = ((p0.w + p1.w) + (p2.w + p3.w)) + ((p4.w + p5.w) + (p6.w + p7.w));
        float off = (sx + sy) + (sz + sw) + smr[256 + j3];

        const int m = m0 + r3;
        const int b = m >> 12, n = m & (N_ - 1);
        const int h = j3 >> 1, pp = j3 & 1;
        out_off[(size_t)((b * H_ + h) * P_ + pp) * N_ + n] = off;
        float f = fminf(fmaxf((float)n + off, 0.f), (float)(2 * N_ - 1));
        idx[((size_t)(b * H_ + h) * N_ + n) * P_ + pp] = (int)f;
    }
}

// ---------------------------------------------------------------------------
// 128x128 m97-style GEMM body: kept for gemm_out (small, 256 blocks).
// ---------------------------------------------------------------------------
template <typename OT>
__device__ __forceinline__ void gemm_body(
    short* smem, const short* __restrict__ A, const short* __restrict__ Bt,
    const float* __restrict__ bias, OT* __restrict__ C, int N, int K, int nx, int lin) {
    short* As = smem;
    short* Bs = smem + 128 * 64;
    const int tid  = threadIdx.x;
    const int lane = tid & 63, w = tid >> 6;
    const int wr = w >> 1, wc = w & 1;
    const int lm = lane & 15, g = lane >> 4;

    const int x8 = lin & 7, t = lin >> 3;
    const int bx = t % nx, by = (t / nx) * 8 + x8;
    const int row0 = by * 128, col0 = bx * 128;

    const short* pa[4];
    const short* pb[4];
#pragma unroll
    for (int r = 0; r < 4; r++) {
        int s   = tid + 256 * r;
        int row = s >> 3, kcs = s & 7;
        int kg  = kcs ^ (row & 7);
        pa[r] = A  + (size_t)(row0 + row) * K + kg * 8;
        pb[r] = Bt + (size_t)(col0 + row) * K + kg * 8;
    }

    v4f acc[4][4];
#pragma unroll
    for (int i = 0; i < 4; i++)
#pragma unroll
        for (int j = 0; j < 4; j++) acc[i][j] = (v4f){0.f, 0.f, 0.f, 0.f};

    for (int k0 = 0; k0 < K; k0 += 64) {
        __syncthreads();
#pragma unroll
        for (int r = 0; r < 4; r++) {
            int s = tid + 256 * r;
            async16(pa[r] + k0, (char*)As + s * 16);
            async16(pb[r] + k0, (char*)Bs + s * 16);
        }
        __syncthreads();
#pragma unroll
        for (int ks = 0; ks < 2; ks++) {
            v8s af[4], bf[4];
#pragma unroll
            for (int i = 0; i < 4; i++) {
                int m   = wr * 64 + i * 16 + lm;
                int sch = m * 8 + ((ks * 4 + g) ^ (m & 7));
                af[i] = *(const v8s*)(As + sch * 8);
            }
#pragma unroll
            for (int j = 0; j < 4; j++) {
                int n   = wc * 64 + j * 16 + lm;
                int sch = n * 8 + ((ks * 4 + g) ^ (n & 7));
                bf[j] = *(const v8s*)(Bs + sch * 8);
            }
#pragma unroll
            for (int i = 0; i < 4; i++)
#pragma unroll
                for (int j = 0; j < 4; j++)
                    acc[i][j] = __builtin_amdgcn_mfma_f32_16x16x32_bf16(af[i], bf[j], acc[i][j], 0, 0, 0);
        }
    }

#pragma unroll
    for (int j = 0; j < 4; j++) {
        int gc = col0 + wc * 64 + j * 16 + lm;
        float bj = bias ? bias[gc] : 0.f;
#pragma unroll
        for (int i = 0; i < 4; i++)
#pragma unroll
            for (int r = 0; r < 4; r++) acc[i][j][r] += bj;
    }

    __syncthreads();
    float* ep = (float*)smem + w * (16 * 68);
#pragma unroll
    for (int i = 0; i < 4; i++) {
#pragma unroll
        for (int j = 0; j < 4; j++)
#pragma unroll
            for (int r = 0; r < 4; r++)
                ep[(g * 4 + r) * 68 + j * 16 + lm] = acc[i][j][r];
        asm volatile("s_waitcnt lgkmcnt(0)" ::: "memory");
        int rr = lane >> 2, cb = (lane & 3) * 16;
        float4 f0 = *(float4*)(ep + rr * 68 + cb + 0);
        float4 f1 = *(float4*)(ep + rr * 68 + cb + 4);
        float4 f2 = *(float4*)(ep + rr * 68 + cb + 8);
        float4 f3 = *(float4*)(ep + rr * 68 + cb + 12);
        asm volatile("s_waitcnt lgkmcnt(0)" ::: "memory");
        int grow = row0 + wr * 64 + i * 16 + rr;
        int gcol = col0 + wc * 64 + cb;
        storeRow(&C[(size_t)grow * N + gcol], f0, f1, f2, f3);
    }
}

// ---------------------------------------------------------------------------
// 256x256 tile, BK=64, 8 waves (2x4). R8: A staged via global_load_lds
// (R3's proven counted-DMA pipeline), B read DIRECT from L2 in
// fragment-panel order (see prep_all). Removes stageB + 8/24 ds_reads/wave
// + B bank conflicts; LDS halves to 64 KiB.
// Per tile T (cur=T&1; A(T+1) in flight to buf cur^1):
//   load bF (8 coalesced global b128)   <- oldest vm after A(T+1)
//   RD_A lo+hi (16 ds_read)
//   lgkm(0); barrier                    <- all waves done reading As[cur]
//   stageA(T+2 -> cur)                  <- safe overwrite
//   MFMA x64 (compiler emits vmcnt(4): waits A(T+1)+bF, leaves A(T+2))
//   barrier                             <- all waves passed their vmcnt
// ---------------------------------------------------------------------------
#define ATILE_ (256 * 64)   // shorts per A tile buffer (32 KiB)

__global__ __launch_bounds__(512, 2) void gemm_qkv_256(
    const short* __restrict__ Aqp, const short* __restrict__ Wq2t,
    const float* __restrict__ bq2, short* __restrict__ qbh,
    const short* __restrict__ Akvp, const short* __restrict__ Wkvt,
    const float* __restrict__ bkv, short* __restrict__ khv) {
    __shared__ short smem[2 * ATILE_];   // 65536 B (A double-buffer only)

    const short* A; const short* Bt; const float* bias; short* C;
    int K, NT, nxs, nwg, lin;
    bool isQ;
    if ((int)blockIdx.x < 128) {
        A = Aqp;  Bt = Wq2t; bias = bq2; C = qbh;
        K = 512; NT = 8; nxs = 1; nwg = 128; lin = blockIdx.x; isQ = true;
    } else {
        A = Akvp; Bt = Wkvt; bias = bkv; C = khv;
        K = 256; NT = 4; nxs = 2; nwg = 512; lin = blockIdx.x - 128; isQ = false;
    }

    const int tid  = threadIdx.x;
    const int lane = tid & 63, w = tid >> 6;
    const int wr = w >> 2, wc = w & 3;          // 2 x 4 wave grid
    const int lm = lane & 15, g = lane >> 4;

    // bijective XCD swizzle (nwg % 8 == 0)
    const int wg = (lin & 7) * (nwg >> 3) + (lin >> 3);
    const int bx = wg & ((1 << nxs) - 1), by = wg >> nxs;
    const int row0 = by << 8, col0 = bx << 8;

    short* As0 = smem;                 // [2][256][64]

    // pre-swizzled global source for A (linear LDS dest; XOR chunk swizzle)
    const int kg = ((tid & 7) ^ ((tid >> 3) & 7)) << 3;
    const short* gA = A + (size_t)(row0 + (tid >> 3)) * K + kg;

    auto stageA = [&](int buf, int k0) {
        char* lp = (char*)(As0 + buf * ATILE_);
#pragma unroll
        for (int r = 0; r < 4; r++)
            async16(gA + (size_t)r * 64 * K + k0, lp + r * 8192 + tid * 16);
    };

    // B fragment-panel base: jt = bx*16 + wc*4 + j, v8s idx =
    //   (jt*NT + T)*128 + (ks*4+g)*16 + lm
    const v8s* Bp = (const v8s*)Bt;
    const int jt0 = bx * 16 + wc * 4;

    v4f acc[8][4];
#pragma unroll
    for (int i = 0; i < 8; i++)
#pragma unroll
        for (int j = 0; j < 4; j++) acc[i][j] = (v4f){0.f, 0.f, 0.f, 0.f};

    float bj[4];
#pragma unroll
    for (int jj = 0; jj < 4; jj++) bj[jj] = bias[col0 + wc * 64 + jj * 16 + lm];

    v8s aLo[4][2], aHi[4][2], bF[4][2];

    auto RD_A = [&](const short* base, int half, v8s (*dst)[2]) {
#pragma unroll
        for (int i = 0; i < 4; i++) {
            const int m = wr * 128 + half * 64 + i * 16 + lm;
#pragma unroll
            for (int ks = 0; ks < 2; ks++)
                dst[i][ks] = *(const v8s*)(base + m * 64 + (((ks << 2) | g) ^ (m & 7)) * 8);
        }
    };
    auto MFMA_H = [&](int half, v8s (*af)[2]) {
        __builtin_amdgcn_s_setprio(1);
#pragma unroll
        for (int i = 0; i < 4; i++)
#pragma unroll
            for (int j = 0; j < 4; j++) {
                acc[half*4+i][j] = __builtin_amdgcn_mfma_f32_16x16x32_bf16(af[i][0], bF[j][0], acc[half*4+i][j], 0, 0, 0);
                acc[half*4+i][j] = __builtin_amdgcn_mfma_f32_16x16x32_bf16(af[i][1], bF[j][1], acc[half*4+i][j], 0, 0, 0);
            }
        __builtin_amdgcn_s_setprio(0);
    };

    // prologue: A(0) -> buf0, A(1) -> buf1
    stageA(0, 0);
    stageA(1, 64);
    asm volatile("s_waitcnt vmcnt(4)" ::: "memory");   // tile0's A landed
    __builtin_amdgcn_s_barrier();
    asm volatile("" ::: "memory");

    for (int T = 0; T < NT; ++T) {
        const int cur = T & 1;
        const short* as = As0 + cur * ATILE_;

        // B fragments: 8 coalesced global b128 loads (L2-hot panels)
#pragma unroll
        for (int j = 0; j < 4; j++)
#pragma unroll
            for (int ks = 0; ks < 2; ks++)
                bF[j][ks] = Bp[(size_t)(jt0 + j) * NT * 128 + (size_t)T * 128 + ((ks << 2) | g) * 16 + lm];

        RD_A(as, 0, aLo);
        RD_A(as, 1, aHi);
        asm volatile("s_waitcnt lgkmcnt(0)" ::: "memory");
        __builtin_amdgcn_s_barrier();       // all waves done reading As[cur]
        if (T + 2 < NT) stageA(cur, (T + 2) << 6);
        MFMA_H(0, aLo);                      // compiler: vmcnt wait for bF
        MFMA_H(1, aHi);
        __builtin_amdgcn_s_barrier();        // all waves passed their vmcnt
        asm volatile("" ::: "memory");
    }

    // epilogue: per-wave 16x64 transpose in LDS; head-major store
    float* ep = (float*)smem + w * (16 * 68);
#pragma unroll
    for (int ii = 0; ii < 8; ii++) {
#pragma unroll
        for (int jj = 0; jj < 4; jj++)
#pragma unroll
            for (int r = 0; r < 4; r++)
                ep[(g * 4 + r) * 68 + jj * 16 + lm] = acc[ii][jj][r] + bj[jj];
        asm volatile("s_waitcnt lgkmcnt(0)" ::: "memory");
        const int rr = lane >> 2, cb = (lane & 3) * 16;
        float4 f0 = *(float4*)(ep + rr * 68 + cb + 0);
        float4 f1 = *(float4*)(ep + rr * 68 + cb + 4);
        float4 f2 = *(float4*)(ep + rr * 68 + cb + 8);
        float4 f3 = *(float4*)(ep + rr * 68 + cb + 12);
        asm volatile("s_waitcnt lgkmcnt(0)" ::: "memory");
        const int grow = row0 + wr * 128 + ii * 16 + rr;
        const int gcol = col0 + wc * 64 + cb;
        short* dst;
        if (isQ) {
            const int h = gcol >> 6;
            dst = C + ((size_t)h * BN_ + grow) * DH_ + (gcol & 63);
        } else {
            const size_t base = (gcol < 512) ? 0 : VOFF_;
            const int h = (gcol >> 6) & 7;
            dst = C + base + ((size_t)h * KVR_ + grow) * DH_ + (gcol & 63);
        }
        storeRowS(dst, f0, f1, f2, f3);
    }
}

// output projection GEMM (old structure; 256 blocks, small)
__global__ __launch_bounds__(256) void gemm_out(
    const short* __restrict__ A, const short* __restrict__ Bt,
    const float* __restrict__ bias, float* __restrict__ C) {
    __shared__ short smem[2 * 128 * 64];
    const int lin = blockIdx.y * gridDim.x + blockIdx.x;
    gemm_body<float>(smem, A, Bt, bias, C, 256, 512, 2, lin);
}

// ---------------------------------------------------------------------------
// Attention: 16-lane groups, 4 samples/wave. Lane owns 4-elem DH slice.
// HEAD-MAJOR inputs: qbh[h][m][64]; khv = Kh[h][r][64] | Vh[h][r][64].
// q pre-scaled by 0.125. attnout stays row-major [m][512] for gemm_out.
// ---------------------------------------------------------------------------
__global__ __launch_bounds__(256) void attn_kernel(
    const short* __restrict__ qbh, const short* __restrict__ khv,
    const int* __restrict__ idx, short* __restrict__ attnout) {
    const int lane = threadIdx.x & 63;
    const int wv   = threadIdx.x >> 6;
    const int s    = lane >> 4, c = lane & 15;
    const int n = blockIdx.x * 16 + wv * 4 + s;
    const int h = blockIdx.y, b = blockIdx.z;
    const int m = b * N_ + n;

    v4s qv = *(const v4s*)(qbh + ((size_t)h * BN_ + m) * DH_ + c * 4);

    const int* ip = idx + ((size_t)(b * H_ + h) * N_ + n) * P_;
    int j0 = ip[0], j1 = ip[1];
    int r0 = b * N_ + j0 + ((j0 >= N_) ? (BN_ - N_) : 0);
    int r1 = b * N_ + j1 + ((j1 >= N_) ? (BN_ - N_) : 0);
    const short* k0p = khv + ((size_t)h * KVR_ + r0) * DH_ + c * 4;
    const short* k1p = khv + ((size_t)h * KVR_ + r1) * DH_ + c * 4;
    v4s k0 = *(const v4s*)k0p, v0 = *(const v4s*)(k0p + VOFF_);
    v4s k1 = *(const v4s*)k1p, v1 = *(const v4s*)(k1p + VOFF_);

    float q0 = b2f(qv[0]), q1 = b2f(qv[1]), q2 = b2f(qv[2]), q3 = b2f(qv[3]);
    float s0 = q0 * b2f(k0[0]) + q1 * b2f(k0[1]) + q2 * b2f(k0[2]) + q3 * b2f(k0[3]);
    float s1 = q0 * b2f(k1[0]) + q1 * b2f(k1[1]) + q2 * b2f(k1[2]) + q3 * b2f(k1[3]);
#pragma unroll
    for (int d = 1; d <= 8; d <<= 1) {
        s0 += __shfl_xor(s0, d);
        s1 += __shfl_xor(s1, d);
    }
    float mx = fmaxf(s0, s1);
    float e0 = __expf(s0 - mx), e1 = __expf(s1 - mx);
    float inv = 1.f / (e0 + e1);
    v4s o;
#pragma unroll
    for (int i = 0; i < 4; i++)
        o[i] = f2b((e0 * b2f(v0[i]) + e1 * b2f(v1[i])) * inv);
    *(v4s*)(attnout + (size_t)m * INNER_ + h * DH_ + c * 4) = o;
}

// ---------------------------------------------------------------------------
extern "C" void kernel_launch(void* const* d_in, const int* in_sizes, int n_in,
                              void* d_out, int out_size, void* d_ws, size_t ws_size,
                              hipStream_t stream) {
    (void)in_sizes; (void)n_in; (void)out_size; (void)ws_size;

    const float* x      = (const float*)d_in[0];
    const float* prevx  = (const float*)d_in[1];
    const float* ln_q_g = (const float*)d_in[2];
    const float* ln_q_b = (const float*)d_in[3];
    const float* ln_k_g = (const float*)d_in[4];
    const float* ln_k_b = (const float*)d_in[5];
    const float* ln_v_g = (const float*)d_in[6];
    const float* ln_v_b = (const float*)d_in[7];
    const float* Wq     = (const float*)d_in[8];
    const float* Wk     = (const float*)d_in[9];
    const float* bk     = (const float*)d_in[10];
    const float* Wv     = (const float*)d_in[11];
    const float* bv     = (const float*)d_in[12];
    const float* Woff   = (const float*)d_in[13];
    const float* boff   = (const float*)d_in[14];
    const float* Wout   = (const float*)d_in[15];
    const float* bout   = (const float*)d_in[16];

    char* cur = (char*)d_ws;
    auto alloc = [&](size_t bytes) { char* p = cur; cur += (bytes + 255) & ~(size_t)255; return p; };
    short* Aq      = (short*)alloc((size_t)BN_ * INNER_ * 2);     // 16 MB
    short* Akv     = (short*)alloc((size_t)KVR_ * DIM_ * 2);      // 16 MB
    short* qbh     = (short*)alloc((size_t)BN_ * INNER_ * 2);     // 16 MB (head-major)
    short* khv     = (short*)alloc((size_t)KVR_ * 1024 * 2);      // 64 MB (Kh|Vh head-major)
    short* attnout = (short*)alloc((size_t)BN_ * INNER_ * 2);     // 16 MB
    short* Wq2t    = (short*)alloc(512 * 512 * 2);                // fragment panels
    short* Wkvt    = (short*)alloc(1024 * 256 * 2);               // fragment panels
    short* Woutb   = (short*)alloc(256 * 512 * 2);
    float* bq2     = (float*)alloc(512 * 4);
    float* bkv     = (float*)alloc(1024 * 4);
    float* Wcomb   = (float*)alloc(512 * 16 * 4);
    float* braw    = (float*)alloc(512 * 16 * 4);
    int*   idxb    = (int*)alloc((size_t)BN_ * 16 * 4);
    // total ~130 MB

    float* out_main = (float*)d_out;                      // (B,N,DIM)
    float* out_off  = out_main + (size_t)BN_ * DIM_;      // (B,H,P,N)

    // 1) merged weight prep + composed offset weights (B in fragment panels)
    prep_all<<<2176, 256, 0, stream>>>(Wq, ln_q_g, ln_q_b,
                                       Wk, ln_k_g, ln_k_b, bk,
                                       Wv, ln_v_g, ln_v_b, bv,
                                       Woff, Wout,
                                       Wq2t, bq2, Wkvt, bkv, Wcomb, braw, Woutb);

    // 2) fused LN + activations + offsets + indices (bcomb folded in)
    norm_fused_kernel<<<BN_ / 16, 256, 0, stream>>>(x, prevx, Wcomb, braw, boff,
                                                    Aq, Akv, out_off, idxb);

    // 3) q + kv projections: A-staged, B-direct fragment panels
    gemm_qkv_256<<<640, 512, 0, stream>>>(Aq, Wq2t, bq2, qbh,
                                          Akv, Wkvt, bkv, khv);

    // 4) gather + softmax(P=2) + weighted sum (head-major K/V gather)
    dim3 ga(N_ / 16, H_, B_);
    attn_kernel<<<ga, 256, 0, stream>>>(qbh, khv, idxb, attnout);

    // 5) output projection
    gemm_out<<<dim3(2, 128), 256, 0, stream>>>(attnout, Woutb, bout, out_main);
}

// Round 9
// 227.873 us; speedup vs baseline: 1.0378x; 1.0378x over previous
//
#include <hip/hip_runtime.h>
#include <hip/hip_bf16.h>
#include <math.h>

#define B_    4
#define N_    4096
#define DIM_  256
#define H_    8
#define DH_   64
#define P_    2
#define INNER_ 512
#define BN_   (B_ * N_)      // 16384 rows for q/out
#define KVR_  (2 * BN_)      // 32768 rows for k/v
#define VOFF_ ((size_t)H_ * KVR_ * DH_)   // shorts offset of V block in khv

typedef short v8s  __attribute__((ext_vector_type(8)));
typedef short v4s  __attribute__((ext_vector_type(4)));
typedef float v4f  __attribute__((ext_vector_type(4)));

__device__ __forceinline__ short f2b(float x) {
    __hip_bfloat16 h = __float2bfloat16(x);
    return *reinterpret_cast<short*>(&h);
}
__device__ __forceinline__ float b2f(short s) {
    __hip_bfloat16 h = *reinterpret_cast<__hip_bfloat16*>(&s);
    return __bfloat162float(h);
}

__device__ __forceinline__ void async16(const void* g, void* l) {
    __builtin_amdgcn_global_load_lds(
        (const __attribute__((address_space(1))) void*)g,
        (__attribute__((address_space(3))) void*)l, 16, 0, 0);
}

__device__ __forceinline__ void storeRow(float* p, float4 f0, float4 f1, float4 f2, float4 f3) {
    ((float4*)p)[0] = f0; ((float4*)p)[1] = f1; ((float4*)p)[2] = f2; ((float4*)p)[3] = f3;
}
__device__ __forceinline__ void storeRowS(short* p, float4 f0, float4 f1, float4 f2, float4 f3) {
    v8s o0, o1;
    o0[0]=f2b(f0.x); o0[1]=f2b(f0.y); o0[2]=f2b(f0.z); o0[3]=f2b(f0.w);
    o0[4]=f2b(f1.x); o0[5]=f2b(f1.y); o0[6]=f2b(f1.z); o0[7]=f2b(f1.w);
    o1[0]=f2b(f2.x); o1[1]=f2b(f2.y); o1[2]=f2b(f2.z); o1[3]=f2b(f2.w);
    o1[4]=f2b(f3.x); o1[5]=f2b(f3.y); o1[6]=f2b(f3.z); o1[7]=f2b(f3.w);
    ((v8s*)p)[0] = o0; ((v8s*)p)[1] = o1;
}

// ---------------------------------------------------------------------------
// MERGED weight prep, one dispatch (R7 layout: row-major Wt [n][K]).
// ---------------------------------------------------------------------------
__global__ __launch_bounds__(256) void prep_all(
    const float* __restrict__ Wq, const float* __restrict__ gq, const float* __restrict__ betaq,
    const float* __restrict__ Wk, const float* __restrict__ gk, const float* __restrict__ betak,
    const float* __restrict__ bk,
    const float* __restrict__ Wv, const float* __restrict__ gv, const float* __restrict__ betav,
    const float* __restrict__ bv,
    const float* __restrict__ Woff, const float* __restrict__ Wout,
    short* __restrict__ Wq2t, float* __restrict__ bq2,
    short* __restrict__ Wkvt, float* __restrict__ bkv,
    float* __restrict__ Wcomb, float* __restrict__ braw, short* __restrict__ Woutb) {
    __shared__ float sm[272];
    const int bid = blockIdx.x, t = threadIdx.x;

    if (bid < 1536) {
        const float *W, *g, *beta, *bias_in;
        short* Wt; float* b2; int K, n; float scale;
        if (bid < 512)       { W=Wq; g=gq; beta=betaq; bias_in=nullptr; Wt=Wq2t; b2=bq2; K=512; n=bid;        scale=0.125f; }
        else if (bid < 1024) { W=Wk; g=gk; beta=betak; bias_in=bk; Wt=Wkvt;           b2=bkv;       K=256; n=bid-512;  scale=1.f; }
        else                 { W=Wv; g=gv; beta=betav; bias_in=bv; Wt=Wkvt+512*256;   b2=bkv+512;   K=256; n=bid-1024; scale=1.f; }
        float partial = 0.f;
        for (int k = t; k < K; k += 256) {
            float w = W[k * 512 + n];
            Wt[(size_t)n * K + k] = f2b(scale * g[k] * w);
            partial += beta[k] * w;
        }
        sm[t] = partial;
        __syncthreads();
        for (int s = 128; s > 0; s >>= 1) {
            if (t < s) sm[t] += sm[t + s];
            __syncthreads();
        }
        if (t == 0) b2[n] = scale * ((bias_in ? bias_in[n] : 0.f) + sm[0]);
    } else if (bid < 2048) {
        const int k = bid - 1536;
        const int hp = t & 15, jg = t >> 4;
        float p = 0.f;
        for (int j = jg; j < INNER_; j += 16)
            p += Wq[k * INNER_ + j] * Woff[hp * INNER_ + j];
        sm[jg * 17 + hp] = p;
        __syncthreads();
        if (t < 16) {
            float s = 0.f;
            for (int i = 0; i < 16; i++) s += sm[i * 17 + t];
            Wcomb[k * 16 + t] = gq[k] * s;
            braw[k * 16 + t]  = betaq[k] * s;
        }
    } else {
        const int i0 = (bid - 2048) * 1024 + t * 4;
        float4 f = *(const float4*)(Wout + i0);
        v4s o;
        o[0] = f2b(f.x); o[1] = f2b(f.y); o[2] = f2b(f.z); o[3] = f2b(f.w);
        *(v4s*)(Woutb + i0) = o;
    }
}

// ---------------------------------------------------------------------------
// FUSED single-pass LN + activations + offsets. One wave per 4 rows.
// (R7 structure + R8 deferred bcomb sync.)
// ---------------------------------------------------------------------------
__global__ __launch_bounds__(256) void norm_fused_kernel(
    const float* __restrict__ x, const float* __restrict__ p,
    const float* __restrict__ Wcomb, const float* __restrict__ braw,
    const float* __restrict__ boff,
    short* __restrict__ Aq, short* __restrict__ Akv,
    float* __restrict__ out_off, int* __restrict__ idx) {
    __shared__ float smr[272];
    __shared__ float sc[4][4][16][33];   // [wave][row][out j][lane<32] (+pad)
    const int t    = threadIdx.x;
    const int lane = t & 63;
    const int wv   = t >> 6;
    const int m0   = (blockIdx.x * 4 + wv) * 4;   // first of 4 rows
    const int k8   = lane * 8;

    // per-block bcomb partials (braw is L2-hot, 32KB)
    {
        const int hp = t & 15, kg = t >> 4;
        float pp = 0.f;
        for (int k = kg; k < 512; k += 16) pp += braw[k * 16 + hp];
        smr[kg * 17 + hp] = pp;
    }
    __syncthreads();
    if (t < 16) {
        float s = 0.f;
#pragma unroll
        for (int i = 0; i < 16; i++) s += smr[i * 17 + t];
        smr[256 + t] = s + boff[t];
    }
    // finalize sync deferred to just before the final reduce.

    float4 w[8][4];
#pragma unroll
    for (int i = 0; i < 8; i++) {
        const float4* wr = (const float4*)(Wcomb + (size_t)(k8 + i) * 16);
#pragma unroll
        for (int j = 0; j < 4; j++) w[i][j] = wr[j];
    }

    const float* srcb = (lane < 32) ? (x + k8) : (p + k8 - DIM_);

    float4 ua[4][2];
#pragma unroll
    for (int r = 0; r < 4; r++) {
        ua[r][0] = ((const float4*)(srcb + (size_t)(m0 + r) * DIM_))[0];
        ua[r][1] = ((const float4*)(srcb + (size_t)(m0 + r) * DIM_))[1];
    }

    float s[4], q2[4];
#pragma unroll
    for (int r = 0; r < 4; r++) {
        float uv[8] = { ua[r][0].x, ua[r][0].y, ua[r][0].z, ua[r][0].w,
                        ua[r][1].x, ua[r][1].y, ua[r][1].z, ua[r][1].w };
        float ss = 0.f, qq = 0.f;
#pragma unroll
        for (int i = 0; i < 8; i++) { ss += uv[i]; qq += uv[i] * uv[i]; }
        s[r] = ss; q2[r] = qq;
    }
#pragma unroll
    for (int d = 1; d <= 16; d <<= 1) {
#pragma unroll
        for (int r = 0; r < 4; r++) {
            s[r]  += __shfl_xor(s[r], d);
            q2[r] += __shfl_xor(q2[r], d);
        }
    }
    float mean_h[4], rstd_h[4], mean_q[4], rstd_q[4];
#pragma unroll
    for (int r = 0; r < 4; r++) {
        mean_h[r] = s[r] * (1.f / 256.f);
        float var_h = q2[r] * (1.f / 256.f) - mean_h[r] * mean_h[r];
        rstd_h[r] = rsqrtf(var_h + 1e-5f);
        float sf  = s[r]  + __shfl_xor(s[r], 32);
        float q2f = q2[r] + __shfl_xor(q2[r], 32);
        mean_q[r] = sf * (1.f / 512.f);
        float var_q = q2f * (1.f / 512.f) - mean_q[r] * mean_q[r];
        rstd_q[r] = rsqrtf(var_q + 1e-5f);
    }

#pragma unroll
    for (int r = 0; r < 4; r++) {
        const int m = m0 + r;
        float uv[8] = { ua[r][0].x, ua[r][0].y, ua[r][0].z, ua[r][0].w,
                        ua[r][1].x, ua[r][1].y, ua[r][1].z, ua[r][1].w };

        v8s okv;
#pragma unroll
        for (int i = 0; i < 8; i++) okv[i] = f2b((uv[i] - mean_h[r]) * rstd_h[r]);
        short* akvdst = Akv + ((lane < 32) ? ((size_t)m * DIM_ + k8)
                                           : ((size_t)(BN_ + m) * DIM_ + k8 - DIM_));
        *(v8s*)akvdst = okv;

        float nv[8];
        v8s oq;
#pragma unroll
        for (int i = 0; i < 8; i++) { nv[i] = (uv[i] - mean_q[r]) * rstd_q[r]; oq[i] = f2b(nv[i]); }
        *(v8s*)(Aq + (size_t)m * INNER_ + k8) = oq;

        float acc[16];
#pragma unroll
        for (int h = 0; h < 16; h++) acc[h] = 0.f;
#pragma unroll
        for (int i = 0; i < 8; i++) {
            float nvi = nv[i];
            acc[0]  += nvi * w[i][0].x;  acc[1]  += nvi * w[i][0].y;
            acc[2]  += nvi * w[i][0].z;  acc[3]  += nvi * w[i][0].w;
            acc[4]  += nvi * w[i][1].x;  acc[5]  += nvi * w[i][1].y;
            acc[6]  += nvi * w[i][1].z;  acc[7]  += nvi * w[i][1].w;
            acc[8]  += nvi * w[i][2].x;  acc[9]  += nvi * w[i][2].y;
            acc[10] += nvi * w[i][2].z;  acc[11] += nvi * w[i][2].w;
            acc[12] += nvi * w[i][3].x;  acc[13] += nvi * w[i][3].y;
            acc[14] += nvi * w[i][3].z;  acc[15] += nvi * w[i][3].w;
        }
#pragma unroll
        for (int j = 0; j < 16; j++) acc[j] += __shfl_xor(acc[j], 32);
        if (lane < 32) {
#pragma unroll
            for (int j = 0; j < 16; j++) sc[wv][r][j][lane] = acc[j];
        }
    }
    asm volatile("s_waitcnt lgkmcnt(0)" ::: "memory");
    __syncthreads();   // smr[256+] finalized (deferred sync)

    {
        const int r3 = lane >> 4, j3 = lane & 15;
        const float* sp = &sc[wv][r3][j3][0];
        float4 p0 = *(const float4*)(sp + 0),  p1 = *(const float4*)(sp + 4);
        float4 p2 = *(const float4*)(sp + 8),  p3 = *(const float4*)(sp + 12);
        float4 p4 = *(const float4*)(sp + 16), p5 = *(const float4*)(sp + 20);
        float4 p6 = *(const float4*)(sp + 24), p7 = *(const float4*)(sp + 28);
        float sx = ((p0.x + p1.x) + (p2.x + p3.x)) + ((p4.x + p5.x) + (p6.x + p7.x));
        float sy = ((p0.y + p1.y) + (p2.y + p3.y)) + ((p4.y + p5.y) + (p6.y + p7.y));
        float sz = ((p0.z + p1.z) + (p2.z + p3.z)) + ((p4.z + p5.z) + (p6.z + p7.z));
        float sw = ((p0.w + p1.w) + (p2.w + p3.w)) + ((p4.w + p5.w) + (p6.w + p7.w));
        float off = (sx + sy) + (sz + sw) + smr[256 + j3];

        const int m = m0 + r3;
        const int b = m >> 12, n = m & (N_ - 1);
        const int h = j3 >> 1, pp = j3 & 1;
        out_off[(size_t)((b * H_ + h) * P_ + pp) * N_ + n] = off;
        float f = fminf(fmaxf((float)n + off, 0.f), (float)(2 * N_ - 1));
        idx[((size_t)(b * H_ + h) * N_ + n) * P_ + pp] = (int)f;
    }
}

// ---------------------------------------------------------------------------
// 256x256 tile, BK=64, 8 waves (2x4), R3's proven 3-barrier counted-vmcnt
// schedule (best measured 45.9us @ R7). Head-major outputs.
// ---------------------------------------------------------------------------
#define ATILE_ (256 * 64)   // shorts per tile buffer (32 KiB)

__global__ __launch_bounds__(512, 2) void gemm_qkv_256(
    const short* __restrict__ Aqp, const short* __restrict__ Wq2t,
    const float* __restrict__ bq2, short* __restrict__ qbh,
    const short* __restrict__ Akvp, const short* __restrict__ Wkvt,
    const float* __restrict__ bkv, short* __restrict__ khv) {
    __shared__ short smem[4 * ATILE_];   // 131072 B

    const short* A; const short* Bt; const float* bias; short* C;
    int K, NT, nxs, nwg, lin;
    bool isQ;
    if ((int)blockIdx.x < 128) {
        A = Aqp;  Bt = Wq2t; bias = bq2; C = qbh;
        K = 512; NT = 8; nxs = 1; nwg = 128; lin = blockIdx.x; isQ = true;
    } else {
        A = Akvp; Bt = Wkvt; bias = bkv; C = khv;
        K = 256; NT = 4; nxs = 2; nwg = 512; lin = blockIdx.x - 128; isQ = false;
    }

    const int tid  = threadIdx.x;
    const int lane = tid & 63, w = tid >> 6;
    const int wr = w >> 2, wc = w & 3;          // 2 x 4 wave grid
    const int lm = lane & 15, g = lane >> 4;

    const int wg = (lin & 7) * (nwg >> 3) + (lin >> 3);
    const int bx = wg & ((1 << nxs) - 1), by = wg >> nxs;
    const int row0 = by << 8, col0 = bx << 8;

    short* As0 = smem;                 // [2][256][64]
    short* Bs0 = smem + 2 * ATILE_;    // [2][256][64]

    const int kg = ((tid & 7) ^ ((tid >> 3) & 7)) << 3;
    const short* gA = A  + (size_t)(row0 + (tid >> 3)) * K + kg;
    const short* gB = Bt + (size_t)(col0 + (tid >> 3)) * K + kg;

    auto stageA = [&](int buf, int k0) {
        char* lp = (char*)(As0 + buf * ATILE_);
#pragma unroll
        for (int r = 0; r < 4; r++)
            async16(gA + (size_t)r * 64 * K + k0, lp + r * 8192 + tid * 16);
    };
    auto stageB = [&](int buf, int k0) {
        char* lp = (char*)(Bs0 + buf * ATILE_);
#pragma unroll
        for (int r = 0; r < 4; r++)
            async16(gB + (size_t)r * 64 * K + k0, lp + r * 8192 + tid * 16);
    };

    v4f acc[8][4];
#pragma unroll
    for (int i = 0; i < 8; i++)
#pragma unroll
        for (int j = 0; j < 4; j++) acc[i][j] = (v4f){0.f, 0.f, 0.f, 0.f};

    float bj[4];
#pragma unroll
    for (int jj = 0; jj < 4; jj++) bj[jj] = bias[col0 + wc * 64 + jj * 16 + lm];

    v8s aLo[4][2], aHi[4][2], bF[4][2];

    auto RD_A = [&](const short* base, int half, v8s (*dst)[2]) {
#pragma unroll
        for (int i = 0; i < 4; i++) {
            const int m = wr * 128 + half * 64 + i * 16 + lm;
#pragma unroll
            for (int ks = 0; ks < 2; ks++)
                dst[i][ks] = *(const v8s*)(base + m * 64 + (((ks << 2) | g) ^ (m & 7)) * 8);
        }
    };
    auto RD_B = [&](const short* base) {
#pragma unroll
        for (int j = 0; j < 4; j++) {
            const int n = wc * 64 + j * 16 + lm;
#pragma unroll
            for (int ks = 0; ks < 2; ks++)
                bF[j][ks] = *(const v8s*)(base + n * 64 + (((ks << 2) | g) ^ (n & 7)) * 8);
        }
    };
    auto MFMA_H = [&](int half, v8s (*af)[2]) {
        __builtin_amdgcn_s_setprio(1);
#pragma unroll
        for (int i = 0; i < 4; i++)
#pragma unroll
            for (int j = 0; j < 4; j++) {
                acc[half*4+i][j] = __builtin_amdgcn_mfma_f32_16x16x32_bf16(af[i][0], bF[j][0], acc[half*4+i][j], 0, 0, 0);
                acc[half*4+i][j] = __builtin_amdgcn_mfma_f32_16x16x32_bf16(af[i][1], bF[j][1], acc[half*4+i][j], 0, 0, 0);
            }
        __builtin_amdgcn_s_setprio(0);
    };

    stageB(0, 0); stageA(0, 0);
    stageB(1, 64); stageA(1, 64);
    asm volatile("s_waitcnt vmcnt(8)" ::: "memory");
    __builtin_amdgcn_s_barrier();
    asm volatile("" ::: "memory");

    for (int T = 0; T < NT; ++T) {
        const int cur = T & 1;
        const short* as = As0 + cur * ATILE_;
        const short* bs = Bs0 + cur * ATILE_;
        const bool s2 = (T + 2 < NT);
        const int k2 = (T + 2) << 6;

        RD_B(bs);
        RD_A(as, 0, aLo);
        asm volatile("s_waitcnt lgkmcnt(0)" ::: "memory");
        __builtin_amdgcn_s_barrier();
        if (s2) stageB(cur, k2);
        MFMA_H(0, aLo);
        RD_A(as, 1, aHi);
        asm volatile("s_waitcnt lgkmcnt(0)" ::: "memory");
        __builtin_amdgcn_s_barrier();
        if (s2) stageA(cur, k2);
        MFMA_H(1, aHi);
        if (s2)              asm volatile("s_waitcnt vmcnt(8)" ::: "memory");
        else if (T + 1 < NT) asm volatile("s_waitcnt vmcnt(0)" ::: "memory");
        __builtin_amdgcn_s_barrier();
        asm volatile("" ::: "memory");
    }

    float* ep = (float*)smem + w * (16 * 68);
#pragma unroll
    for (int ii = 0; ii < 8; ii++) {
#pragma unroll
        for (int jj = 0; jj < 4; jj++)
#pragma unroll
            for (int r = 0; r < 4; r++)
                ep[(g * 4 + r) * 68 + jj * 16 + lm] = acc[ii][jj][r] + bj[jj];
        asm volatile("s_waitcnt lgkmcnt(0)" ::: "memory");
        const int rr = lane >> 2, cb = (lane & 3) * 16;
        float4 f0 = *(float4*)(ep + rr * 68 + cb + 0);
        float4 f1 = *(float4*)(ep + rr * 68 + cb + 4);
        float4 f2 = *(float4*)(ep + rr * 68 + cb + 8);
        float4 f3 = *(float4*)(ep + rr * 68 + cb + 12);
        asm volatile("s_waitcnt lgkmcnt(0)" ::: "memory");
        const int grow = row0 + wr * 128 + ii * 16 + rr;
        const int gcol = col0 + wc * 64 + cb;
        short* dst;
        if (isQ) {
            const int h = gcol >> 6;
            dst = C + ((size_t)h * BN_ + grow) * DH_ + (gcol & 63);
        } else {
            const size_t base = (gcol < 512) ? 0 : VOFF_;
            const int h = (gcol >> 6) & 7;
            dst = C + base + ((size_t)h * KVR_ + grow) * DH_ + (gcol & 63);
        }
        storeRowS(dst, f0, f1, f2, f3);
    }
}

// ---------------------------------------------------------------------------
// R9 FUSED attention + output projection. 256 blocks x 256 thr (4 waves).
// Block = 64 output rows x all 256 cols.
//  phase 1: attn for 64 rows x 8 heads -> As[64][512] bf16 in LDS,
//           stored XOR-granule-swizzled for conflict-free b128 frag reads.
//  phase 2: counted-vmcnt double-buffered GEMM (K=512) vs Woutb, A from LDS.
// Eliminates the 16MB attnout write + 16MB read + one dispatch.
// LDS: A 64KB + B 2x32KB = 128KB -> 1 block/CU.
// ---------------------------------------------------------------------------
__global__ __launch_bounds__(256) void attn_out_kernel(
    const short* __restrict__ qbh, const short* __restrict__ khv,
    const int* __restrict__ idx, const short* __restrict__ Woutb,
    const float* __restrict__ bout, float* __restrict__ C) {
    __shared__ short As[64 * 512];       // 64 KB (swizzled attn result)
    __shared__ short Bs[2][256 * 64];    // 2 x 32 KB B tiles
    const int tid  = threadIdx.x;
    const int lane = tid & 63, wv = tid >> 6;   // 4 waves (wave = col quarter)
    const int sg   = lane >> 4, c = lane & 15;  // 16-lane attn groups
    const int lm   = c, g = sg;                 // frag coords
    const int m0   = blockIdx.x * 64;

    // ---------------- phase 1: attention -> As ----------------
#pragma unroll 2
    for (int pass = 0; pass < 32; ++pass) {
        const int task = pass * 16 + wv * 4 + sg;   // 0..511
        const int mloc = task >> 3, h = task & 7;
        const int m = m0 + mloc;
        const int b = m >> 12, n = m & (N_ - 1);

        v4s qv = *(const v4s*)(qbh + ((size_t)h * BN_ + m) * DH_ + c * 4);
        const int* ip = idx + ((size_t)(b * H_ + h) * N_ + n) * P_;
        int j0 = ip[0], j1 = ip[1];
        int r0 = b * N_ + j0 + ((j0 >= N_) ? (BN_ - N_) : 0);
        int r1 = b * N_ + j1 + ((j1 >= N_) ? (BN_ - N_) : 0);
        const short* k0p = khv + ((size_t)h * KVR_ + r0) * DH_ + c * 4;
        const short* k1p = khv + ((size_t)h * KVR_ + r1) * DH_ + c * 4;
        v4s k0 = *(const v4s*)k0p, v0 = *(const v4s*)(k0p + VOFF_);
        v4s k1 = *(const v4s*)k1p, v1 = *(const v4s*)(k1p + VOFF_);

        float q0 = b2f(qv[0]), q1 = b2f(qv[1]), q2 = b2f(qv[2]), q3 = b2f(qv[3]);
        float s0 = q0 * b2f(k0[0]) + q1 * b2f(k0[1]) + q2 * b2f(k0[2]) + q3 * b2f(k0[3]);
        float s1 = q0 * b2f(k1[0]) + q1 * b2f(k1[1]) + q2 * b2f(k1[2]) + q3 * b2f(k1[3]);
#pragma unroll
        for (int d = 1; d <= 8; d <<= 1) {
            s0 += __shfl_xor(s0, d);
            s1 += __shfl_xor(s1, d);
        }
        float mx = fmaxf(s0, s1);
        float e0 = __expf(s0 - mx), e1 = __expf(s1 - mx);
        float inv = 1.f / (e0 + e1);
        v4s o;
#pragma unroll
        for (int i = 0; i < 4; i++)
            o[i] = f2b((e0 * b2f(v0[i]) + e1 * b2f(v1[i])) * inv);
        // swizzled store: granule g0 = h*8 + (c>>1); low-3 bits XOR mloc&7
        const int g0  = h * 8 + (c >> 1);
        const int swz = g0 ^ (mloc & 7);
        *(v4s*)(As + mloc * 512 + swz * 8 + (c & 1) * 4) = o;
    }
    __syncthreads();

    // ---------------- phase 2: GEMM out = As @ Woutb^T + bout ------------
    auto stageB = [&](int buf, int T) {
#pragma unroll
        for (int r = 0; r < 8; r++) {
            int sI = tid + 256 * r;            // 0..2047
            int row = sI >> 3, kc = sI & 7;
            int kgg = kc ^ (row & 7);
            async16(Woutb + (size_t)row * 512 + T * 64 + kgg * 8,
                    (char*)(&Bs[buf][0]) + sI * 16);
        }
    };

    v4f acc[4][4];
#pragma unroll
    for (int i = 0; i < 4; i++)
#pragma unroll
        for (int j = 0; j < 4; j++) acc[i][j] = (v4f){0.f, 0.f, 0.f, 0.f};

    float bj[4];
#pragma unroll
    for (int j = 0; j < 4; j++) bj[j] = bout[wv * 64 + j * 16 + lm];

    stageB(0, 0); stageB(1, 1);
    asm volatile("s_waitcnt vmcnt(8)" ::: "memory");
    __builtin_amdgcn_s_barrier();
    asm volatile("" ::: "memory");

    for (int T = 0; T < 8; ++T) {
        const int cur = T & 1;
        v8s af[4][2], bf[4][2];
#pragma unroll
        for (int i = 0; i < 4; i++) {
            const int m = i * 16 + lm;
#pragma unroll
            for (int ks = 0; ks < 2; ks++) {
                const int gr = T * 8 + (((ks << 2) | g) ^ (m & 7));
                af[i][ks] = *(const v8s*)(As + m * 512 + gr * 8);
            }
        }
#pragma unroll
        for (int j = 0; j < 4; j++) {
            const int col = wv * 64 + j * 16 + lm;
#pragma unroll
            for (int ks = 0; ks < 2; ks++)
                bf[j][ks] = *(const v8s*)(&Bs[cur][0] + col * 64 + ((((ks << 2) | g)) ^ (col & 7)) * 8);
        }
        asm volatile("s_waitcnt lgkmcnt(0)" ::: "memory");
        __builtin_amdgcn_s_barrier();       // all waves done reading Bs[cur]
        if (T + 2 < 8) stageB(cur, T + 2);
        __builtin_amdgcn_s_setprio(1);
#pragma unroll
        for (int i = 0; i < 4; i++)
#pragma unroll
            for (int j = 0; j < 4; j++) {
                acc[i][j] = __builtin_amdgcn_mfma_f32_16x16x32_bf16(af[i][0], bf[j][0], acc[i][j], 0, 0, 0);
                acc[i][j] = __builtin_amdgcn_mfma_f32_16x16x32_bf16(af[i][1], bf[j][1], acc[i][j], 0, 0, 0);
            }
        __builtin_amdgcn_s_setprio(0);
        if (T + 2 < 8)      asm volatile("s_waitcnt vmcnt(8)" ::: "memory");
        else if (T + 1 < 8) asm volatile("s_waitcnt vmcnt(0)" ::: "memory");
        __builtin_amdgcn_s_barrier();
        asm volatile("" ::: "memory");
    }

    __syncthreads();   // all waves finished As reads before ep aliases it
    float* ep = (float*)As + wv * (16 * 68);
#pragma unroll
    for (int i = 0; i < 4; i++) {
#pragma unroll
        for (int j = 0; j < 4; j++)
#pragma unroll
            for (int r = 0; r < 4; r++)
                ep[(g * 4 + r) * 68 + j * 16 + lm] = acc[i][j][r] + bj[j];
        asm volatile("s_waitcnt lgkmcnt(0)" ::: "memory");
        const int rr = lane >> 2, cb = (lane & 3) * 16;
        float4 f0 = *(float4*)(ep + rr * 68 + cb + 0);
        float4 f1 = *(float4*)(ep + rr * 68 + cb + 4);
        float4 f2 = *(float4*)(ep + rr * 68 + cb + 8);
        float4 f3 = *(float4*)(ep + rr * 68 + cb + 12);
        asm volatile("s_waitcnt lgkmcnt(0)" ::: "memory");
        const int grow = m0 + i * 16 + rr;
        const int gcol = wv * 64 + cb;
        storeRow(&C[(size_t)grow * DIM_ + gcol], f0, f1, f2, f3);
    }
}

// ---------------------------------------------------------------------------
extern "C" void kernel_launch(void* const* d_in, const int* in_sizes, int n_in,
                              void* d_out, int out_size, void* d_ws, size_t ws_size,
                              hipStream_t stream) {
    (void)in_sizes; (void)n_in; (void)out_size; (void)ws_size;

    const float* x      = (const float*)d_in[0];
    const float* prevx  = (const float*)d_in[1];
    const float* ln_q_g = (const float*)d_in[2];
    const float* ln_q_b = (const float*)d_in[3];
    const float* ln_k_g = (const float*)d_in[4];
    const float* ln_k_b = (const float*)d_in[5];
    const float* ln_v_g = (const float*)d_in[6];
    const float* ln_v_b = (const float*)d_in[7];
    const float* Wq     = (const float*)d_in[8];
    const float* Wk     = (const float*)d_in[9];
    const float* bk     = (const float*)d_in[10];
    const float* Wv     = (const float*)d_in[11];
    const float* bv     = (const float*)d_in[12];
    const float* Woff   = (const float*)d_in[13];
    const float* boff   = (const float*)d_in[14];
    const float* Wout   = (const float*)d_in[15];
    const float* bout   = (const float*)d_in[16];

    char* cur = (char*)d_ws;
    auto alloc = [&](size_t bytes) { char* p = cur; cur += (bytes + 255) & ~(size_t)255; return p; };
    short* Aq      = (short*)alloc((size_t)BN_ * INNER_ * 2);     // 16 MB
    short* Akv     = (short*)alloc((size_t)KVR_ * DIM_ * 2);      // 16 MB
    short* qbh     = (short*)alloc((size_t)BN_ * INNER_ * 2);     // 16 MB (head-major)
    short* khv     = (short*)alloc((size_t)KVR_ * 1024 * 2);      // 64 MB (Kh|Vh head-major)
    short* Wq2t    = (short*)alloc(512 * 512 * 2);
    short* Wkvt    = (short*)alloc(1024 * 256 * 2);
    short* Woutb   = (short*)alloc(256 * 512 * 2);
    float* bq2     = (float*)alloc(512 * 4);
    float* bkv     = (float*)alloc(1024 * 4);
    float* Wcomb   = (float*)alloc(512 * 16 * 4);
    float* braw    = (float*)alloc(512 * 16 * 4);
    int*   idxb    = (int*)alloc((size_t)BN_ * 16 * 4);
    // total ~115 MB

    float* out_main = (float*)d_out;                      // (B,N,DIM)
    float* out_off  = out_main + (size_t)BN_ * DIM_;      // (B,H,P,N)

    // 1) merged weight prep + composed offset weights
    prep_all<<<2176, 256, 0, stream>>>(Wq, ln_q_g, ln_q_b,
                                       Wk, ln_k_g, ln_k_b, bk,
                                       Wv, ln_v_g, ln_v_b, bv,
                                       Woff, Wout,
                                       Wq2t, bq2, Wkvt, bkv, Wcomb, braw, Woutb);

    // 2) fused LN + activations + offsets + indices
    norm_fused_kernel<<<BN_ / 16, 256, 0, stream>>>(x, prevx, Wcomb, braw, boff,
                                                    Aq, Akv, out_off, idxb);

    // 3) q + kv projections (R3/R7 schedule, head-major out)
    gemm_qkv_256<<<640, 512, 0, stream>>>(Aq, Wq2t, bq2, qbh,
                                          Akv, Wkvt, bkv, khv);

    // 4) FUSED attention + output projection (one dispatch)
    attn_out_kernel<<<256, 256, 0, stream>>>(qbh, khv, idxb, Woutb, bout, out_main);
}

// Round 10
// 214.747 us; speedup vs baseline: 1.1012x; 1.0611x over previous
//
#include <hip/hip_runtime.h>
#include <hip/hip_bf16.h>
#include <math.h>

#define B_    4
#define N_    4096
#define DIM_  256
#define H_    8
#define DH_   64
#define P_    2
#define INNER_ 512
#define BN_   (B_ * N_)      // 16384 rows for q/out
#define KVR_  (2 * BN_)      // 32768 rows for k/v

typedef short v8s  __attribute__((ext_vector_type(8)));
typedef short v4s  __attribute__((ext_vector_type(4)));
typedef float v4f  __attribute__((ext_vector_type(4)));

__device__ __forceinline__ short f2b(float x) {
    __hip_bfloat16 h = __float2bfloat16(x);
    return *reinterpret_cast<short*>(&h);
}
__device__ __forceinline__ float b2f(short s) {
    __hip_bfloat16 h = *reinterpret_cast<__hip_bfloat16*>(&s);
    return __bfloat162float(h);
}

__device__ __forceinline__ void async16(const void* g, void* l) {
    __builtin_amdgcn_global_load_lds(
        (const __attribute__((address_space(1))) void*)g,
        (__attribute__((address_space(3))) void*)l, 16, 0, 0);
}

__device__ __forceinline__ void storeRow(float* p, float4 f0, float4 f1, float4 f2, float4 f3) {
    ((float4*)p)[0] = f0; ((float4*)p)[1] = f1; ((float4*)p)[2] = f2; ((float4*)p)[3] = f3;
}
__device__ __forceinline__ void storeRow(__hip_bfloat16* p, float4 f0, float4 f1, float4 f2, float4 f3) {
    v8s o0, o1;
    o0[0]=f2b(f0.x); o0[1]=f2b(f0.y); o0[2]=f2b(f0.z); o0[3]=f2b(f0.w);
    o0[4]=f2b(f1.x); o0[5]=f2b(f1.y); o0[6]=f2b(f1.z); o0[7]=f2b(f1.w);
    o1[0]=f2b(f2.x); o1[1]=f2b(f2.y); o1[2]=f2b(f2.z); o1[3]=f2b(f2.w);
    o1[4]=f2b(f3.x); o1[5]=f2b(f3.y); o1[6]=f2b(f3.z); o1[7]=f2b(f3.w);
    ((v8s*)p)[0] = o0; ((v8s*)p)[1] = o1;
}

// ---------------------------------------------------------------------------
// MERGED weight prep, one dispatch (row-major Wt [n][K], as R3).
// ---------------------------------------------------------------------------
__global__ __launch_bounds__(256) void prep_all(
    const float* __restrict__ Wq, const float* __restrict__ gq, const float* __restrict__ betaq,
    const float* __restrict__ Wk, const float* __restrict__ gk, const float* __restrict__ betak,
    const float* __restrict__ bk,
    const float* __restrict__ Wv, const float* __restrict__ gv, const float* __restrict__ betav,
    const float* __restrict__ bv,
    const float* __restrict__ Woff, const float* __restrict__ Wout,
    short* __restrict__ Wq2t, float* __restrict__ bq2,
    short* __restrict__ Wkvt, float* __restrict__ bkv,
    float* __restrict__ Wcomb, float* __restrict__ braw, short* __restrict__ Woutb) {
    __shared__ float sm[272];
    const int bid = blockIdx.x, t = threadIdx.x;

    if (bid < 1536) {
        const float *W, *g, *beta, *bias_in;
        short* Wt; float* b2; int K, n; float scale;
        if (bid < 512)       { W=Wq; g=gq; beta=betaq; bias_in=nullptr; Wt=Wq2t; b2=bq2; K=512; n=bid;        scale=0.125f; }
        else if (bid < 1024) { W=Wk; g=gk; beta=betak; bias_in=bk; Wt=Wkvt;           b2=bkv;       K=256; n=bid-512;  scale=1.f; }
        else                 { W=Wv; g=gv; beta=betav; bias_in=bv; Wt=Wkvt+512*256;   b2=bkv+512;   K=256; n=bid-1024; scale=1.f; }
        float partial = 0.f;
        for (int k = t; k < K; k += 256) {
            float w = W[k * 512 + n];
            Wt[(size_t)n * K + k] = f2b(scale * g[k] * w);
            partial += beta[k] * w;
        }
        sm[t] = partial;
        __syncthreads();
        for (int s = 128; s > 0; s >>= 1) {
            if (t < s) sm[t] += sm[t + s];
            __syncthreads();
        }
        if (t == 0) b2[n] = scale * ((bias_in ? bias_in[n] : 0.f) + sm[0]);
    } else if (bid < 2048) {
        const int k = bid - 1536;
        const int hp = t & 15, jg = t >> 4;
        float p = 0.f;
        for (int j = jg; j < INNER_; j += 16)
            p += Wq[k * INNER_ + j] * Woff[hp * INNER_ + j];
        sm[jg * 17 + hp] = p;
        __syncthreads();
        if (t < 16) {
            float s = 0.f;
            for (int i = 0; i < 16; i++) s += sm[i * 17 + t];
            Wcomb[k * 16 + t] = gq[k] * s;
            braw[k * 16 + t]  = betaq[k] * s;
        }
    } else {
        const int i0 = (bid - 2048) * 1024 + t * 4;
        float4 f = *(const float4*)(Wout + i0);
        v4s o;
        o[0] = f2b(f.x); o[1] = f2b(f.y); o[2] = f2b(f.z); o[3] = f2b(f.w);
        *(v4s*)(Woutb + i0) = o;
    }
}

// bcomb[hp] = sum_k braw[k][hp] + boff[hp]  (deterministic 1-block reduce;
// kept as its own tiny dispatch -- folding it into norm's 1024 blocks
// measurably slowed norm (R6-R9 vs R2/R3 evidence)).
__global__ void bcomb_sum(const float* __restrict__ braw, const float* __restrict__ boff,
                          float* __restrict__ bcomb) {
    __shared__ float sm[272];
    int t = threadIdx.x;
    int hp = t & 15, kg = t >> 4;
    float p = 0.f;
    for (int k = kg; k < 512; k += 16) p += braw[k * 16 + hp];
    sm[kg * 17 + hp] = p;
    __syncthreads();
    if (t < 16) {
        float s = 0.f;
        for (int i = 0; i < 16; i++) s += sm[i * 17 + t];
        bcomb[t] = s + boff[t];
    }
}

// ---------------------------------------------------------------------------
// FUSED single-pass LN + activations + offsets. One wave per 4 rows.
// R7 internals (interleaved stats chains; depth-1 fold + LDS-partial offset
// reduce) + bcomb read from global (no per-block braw reduction).
// ---------------------------------------------------------------------------
__global__ __launch_bounds__(256) void norm_fused_kernel(
    const float* __restrict__ x, const float* __restrict__ p,
    const float* __restrict__ Wcomb, const float* __restrict__ bcomb,
    short* __restrict__ Aq, short* __restrict__ Akv,
    float* __restrict__ out_off, int* __restrict__ idx) {
    __shared__ float sc[4][4][16][33];   // [wave][row][out j][lane<32] (+pad)
    const int t    = threadIdx.x;
    const int lane = t & 63;
    const int wv   = t >> 6;
    const int m0   = (blockIdx.x * 4 + wv) * 4;   // first of 4 rows
    const int k8   = lane * 8;

    float4 w[8][4];
#pragma unroll
    for (int i = 0; i < 8; i++) {
        const float4* wr = (const float4*)(Wcomb + (size_t)(k8 + i) * 16);
#pragma unroll
        for (int j = 0; j < 4; j++) w[i][j] = wr[j];
    }

    const float* srcb = (lane < 32) ? (x + k8) : (p + k8 - DIM_);

    // load all 4 rows up front (independent)
    float4 ua[4][2];
#pragma unroll
    for (int r = 0; r < 4; r++) {
        ua[r][0] = ((const float4*)(srcb + (size_t)(m0 + r) * DIM_))[0];
        ua[r][1] = ((const float4*)(srcb + (size_t)(m0 + r) * DIM_))[1];
    }

    // interleaved stats: 4 independent shuffle chains
    float s[4], q2[4];
#pragma unroll
    for (int r = 0; r < 4; r++) {
        float uv[8] = { ua[r][0].x, ua[r][0].y, ua[r][0].z, ua[r][0].w,
                        ua[r][1].x, ua[r][1].y, ua[r][1].z, ua[r][1].w };
        float ss = 0.f, qq = 0.f;
#pragma unroll
        for (int i = 0; i < 8; i++) { ss += uv[i]; qq += uv[i] * uv[i]; }
        s[r] = ss; q2[r] = qq;
    }
#pragma unroll
    for (int d = 1; d <= 16; d <<= 1) {
#pragma unroll
        for (int r = 0; r < 4; r++) {
            s[r]  += __shfl_xor(s[r], d);
            q2[r] += __shfl_xor(q2[r], d);
        }
    }
    float mean_h[4], rstd_h[4], mean_q[4], rstd_q[4];
#pragma unroll
    for (int r = 0; r < 4; r++) {
        mean_h[r] = s[r] * (1.f / 256.f);
        float var_h = q2[r] * (1.f / 256.f) - mean_h[r] * mean_h[r];
        rstd_h[r] = rsqrtf(var_h + 1e-5f);
        float sf  = s[r]  + __shfl_xor(s[r], 32);
        float q2f = q2[r] + __shfl_xor(q2[r], 32);
        mean_q[r] = sf * (1.f / 512.f);
        float var_q = q2f * (1.f / 512.f) - mean_q[r] * mean_q[r];
        rstd_q[r] = rsqrtf(var_q + 1e-5f);
    }

    // per-row: normalize, store activations, partial offset dot
#pragma unroll
    for (int r = 0; r < 4; r++) {
        const int m = m0 + r;
        float uv[8] = { ua[r][0].x, ua[r][0].y, ua[r][0].z, ua[r][0].w,
                        ua[r][1].x, ua[r][1].y, ua[r][1].z, ua[r][1].w };

        v8s okv;
#pragma unroll
        for (int i = 0; i < 8; i++) okv[i] = f2b((uv[i] - mean_h[r]) * rstd_h[r]);
        short* akvdst = Akv + ((lane < 32) ? ((size_t)m * DIM_ + k8)
                                           : ((size_t)(BN_ + m) * DIM_ + k8 - DIM_));
        *(v8s*)akvdst = okv;

        float nv[8];
        v8s oq;
#pragma unroll
        for (int i = 0; i < 8; i++) { nv[i] = (uv[i] - mean_q[r]) * rstd_q[r]; oq[i] = f2b(nv[i]); }
        *(v8s*)(Aq + (size_t)m * INNER_ + k8) = oq;

        float acc[16];
#pragma unroll
        for (int h = 0; h < 16; h++) acc[h] = 0.f;
#pragma unroll
        for (int i = 0; i < 8; i++) {
            float nvi = nv[i];
            acc[0]  += nvi * w[i][0].x;  acc[1]  += nvi * w[i][0].y;
            acc[2]  += nvi * w[i][0].z;  acc[3]  += nvi * w[i][0].w;
            acc[4]  += nvi * w[i][1].x;  acc[5]  += nvi * w[i][1].y;
            acc[6]  += nvi * w[i][1].z;  acc[7]  += nvi * w[i][1].w;
            acc[8]  += nvi * w[i][2].x;  acc[9]  += nvi * w[i][2].y;
            acc[10] += nvi * w[i][2].z;  acc[11] += nvi * w[i][2].w;
            acc[12] += nvi * w[i][3].x;  acc[13] += nvi * w[i][3].y;
            acc[14] += nvi * w[i][3].z;  acc[15] += nvi * w[i][3].w;
        }
        // fold lane <-> lane+32 (depth-1), park partials in LDS
#pragma unroll
        for (int j = 0; j < 16; j++) acc[j] += __shfl_xor(acc[j], 32);
        if (lane < 32) {
#pragma unroll
            for (int j = 0; j < 16; j++) sc[wv][r][j][lane] = acc[j];
        }
    }
    asm volatile("s_waitcnt lgkmcnt(0)" ::: "memory");   // wave-local LDS visible

    // final reduce: all 64 lanes, lane = r*16 + j
    {
        const int r3 = lane >> 4, j3 = lane & 15;
        const float* sp = &sc[wv][r3][j3][0];
        float4 p0 = *(const float4*)(sp + 0),  p1 = *(const float4*)(sp + 4);
        float4 p2 = *(const float4*)(sp + 8),  p3 = *(const float4*)(sp + 12);
        float4 p4 = *(const float4*)(sp + 16), p5 = *(const float4*)(sp + 20);
        float4 p6 = *(const float4*)(sp + 24), p7 = *(const float4*)(sp + 28);
        float sx = ((p0.x + p1.x) + (p2.x + p3.x)) + ((p4.x + p5.x) + (p6.x + p7.x));
        float sy = ((p0.y + p1.y) + (p2.y + p3.y)) + ((p4.y + p5.y) + (p6.y + p7.y));
        float sz = ((p0.z + p1.z) + (p2.z + p3.z)) + ((p4.z + p5.z) + (p6.z + p7.z));
        float sw = ((p0.w + p1.w) + (p2.w + p3.w)) + ((p4.w + p5.w) + (p6.w + p7.w));
        float off = (sx + sy) + (sz + sw) + bcomb[j3];

        const int m = m0 + r3;
        const int b = m >> 12, n = m & (N_ - 1);
        const int h = j3 >> 1, pp = j3 & 1;
        out_off[(size_t)((b * H_ + h) * P_ + pp) * N_ + n] = off;
        float f = fminf(fmaxf((float)n + off, 0.f), (float)(2 * N_ - 1));
        idx[((size_t)(b * H_ + h) * N_ + n) * P_ + pp] = (int)f;
    }
}

// ---------------------------------------------------------------------------
// 128x128 m97-style GEMM body: kept for gemm_out (small, 256 blocks).
// ---------------------------------------------------------------------------
template <typename OT>
__device__ __forceinline__ void gemm_body(
    short* smem, const short* __restrict__ A, const short* __restrict__ Bt,
    const float* __restrict__ bias, OT* __restrict__ C, int N, int K, int nx, int lin) {
    short* As = smem;
    short* Bs = smem + 128 * 64;
    const int tid  = threadIdx.x;
    const int lane = tid & 63, w = tid >> 6;
    const int wr = w >> 1, wc = w & 1;
    const int lm = lane & 15, g = lane >> 4;

    const int x8 = lin & 7, t = lin >> 3;
    const int bx = t % nx, by = (t / nx) * 8 + x8;
    const int row0 = by * 128, col0 = bx * 128;

    const short* pa[4];
    const short* pb[4];
#pragma unroll
    for (int r = 0; r < 4; r++) {
        int s   = tid + 256 * r;
        int row = s >> 3, kcs = s & 7;
        int kg  = kcs ^ (row & 7);
        pa[r] = A  + (size_t)(row0 + row) * K + kg * 8;
        pb[r] = Bt + (size_t)(col0 + row) * K + kg * 8;
    }

    v4f acc[4][4];
#pragma unroll
    for (int i = 0; i < 4; i++)
#pragma unroll
        for (int j = 0; j < 4; j++) acc[i][j] = (v4f){0.f, 0.f, 0.f, 0.f};

    for (int k0 = 0; k0 < K; k0 += 64) {
        __syncthreads();
#pragma unroll
        for (int r = 0; r < 4; r++) {
            int s = tid + 256 * r;
            async16(pa[r] + k0, (char*)As + s * 16);
            async16(pb[r] + k0, (char*)Bs + s * 16);
        }
        __syncthreads();
#pragma unroll
        for (int ks = 0; ks < 2; ks++) {
            v8s af[4], bf[4];
#pragma unroll
            for (int i = 0; i < 4; i++) {
                int m   = wr * 64 + i * 16 + lm;
                int sch = m * 8 + ((ks * 4 + g) ^ (m & 7));
                af[i] = *(const v8s*)(As + sch * 8);
            }
#pragma unroll
            for (int j = 0; j < 4; j++) {
                int n   = wc * 64 + j * 16 + lm;
                int sch = n * 8 + ((ks * 4 + g) ^ (n & 7));
                bf[j] = *(const v8s*)(Bs + sch * 8);
            }
#pragma unroll
            for (int i = 0; i < 4; i++)
#pragma unroll
                for (int j = 0; j < 4; j++)
                    acc[i][j] = __builtin_amdgcn_mfma_f32_16x16x32_bf16(af[i], bf[j], acc[i][j], 0, 0, 0);
        }
    }

#pragma unroll
    for (int j = 0; j < 4; j++) {
        int gc = col0 + wc * 64 + j * 16 + lm;
        float bj = bias ? bias[gc] : 0.f;
#pragma unroll
        for (int i = 0; i < 4; i++)
#pragma unroll
            for (int r = 0; r < 4; r++) acc[i][j][r] += bj;
    }

    __syncthreads();
    float* ep = (float*)smem + w * (16 * 68);
#pragma unroll
    for (int i = 0; i < 4; i++) {
#pragma unroll
        for (int j = 0; j < 4; j++)
#pragma unroll
            for (int r = 0; r < 4; r++)
                ep[(g * 4 + r) * 68 + j * 16 + lm] = acc[i][j][r];
        asm volatile("s_waitcnt lgkmcnt(0)" ::: "memory");
        int rr = lane >> 2, cb = (lane & 3) * 16;
        float4 f0 = *(float4*)(ep + rr * 68 + cb + 0);
        float4 f1 = *(float4*)(ep + rr * 68 + cb + 4);
        float4 f2 = *(float4*)(ep + rr * 68 + cb + 8);
        float4 f3 = *(float4*)(ep + rr * 68 + cb + 12);
        asm volatile("s_waitcnt lgkmcnt(0)" ::: "memory");
        int grow = row0 + wr * 64 + i * 16 + rr;
        int gcol = col0 + wc * 64 + cb;
        storeRow(&C[(size_t)grow * N + gcol], f0, f1, f2, f3);
    }
}

// ---------------------------------------------------------------------------
// 256x256 tile, BK=64, 8 waves (2x4), R3's 3-barrier counted-vmcnt schedule
// (best measured gemm: 45.2us). Row-major outputs (as R3).
// ---------------------------------------------------------------------------
#define ATILE_ (256 * 64)   // shorts per tile buffer (32 KiB)

__global__ __launch_bounds__(512, 2) void gemm_qkv_256(
    const short* __restrict__ Aqp, const short* __restrict__ Wq2t,
    const float* __restrict__ bq2, __hip_bfloat16* __restrict__ qb,
    const short* __restrict__ Akvp, const short* __restrict__ Wkvt,
    const float* __restrict__ bkv, __hip_bfloat16* __restrict__ kvproj) {
    __shared__ short smem[4 * ATILE_];   // 131072 B

    const short* A; const short* Bt; const float* bias; __hip_bfloat16* C;
    int N, K, NT, nxs, nwg, lin;
    if ((int)blockIdx.x < 128) {
        A = Aqp;  Bt = Wq2t; bias = bq2; C = qb;
        N = 512;  K = 512; NT = 8; nxs = 1; nwg = 128; lin = blockIdx.x;
    } else {
        A = Akvp; Bt = Wkvt; bias = bkv; C = kvproj;
        N = 1024; K = 256; NT = 4; nxs = 2; nwg = 512; lin = blockIdx.x - 128;
    }

    const int tid  = threadIdx.x;
    const int lane = tid & 63, w = tid >> 6;
    const int wr = w >> 2, wc = w & 3;          // 2 x 4 wave grid
    const int lm = lane & 15, g = lane >> 4;

    const int wg = (lin & 7) * (nwg >> 3) + (lin >> 3);
    const int bx = wg & ((1 << nxs) - 1), by = wg >> nxs;
    const int row0 = by << 8, col0 = bx << 8;

    short* As0 = smem;                 // [2][256][64]
    short* Bs0 = smem + 2 * ATILE_;    // [2][256][64]

    const int kg = ((tid & 7) ^ ((tid >> 3) & 7)) << 3;
    const short* gA = A  + (size_t)(row0 + (tid >> 3)) * K + kg;
    const short* gB = Bt + (size_t)(col0 + (tid >> 3)) * K + kg;

    auto stageA = [&](int buf, int k0) {
        char* lp = (char*)(As0 + buf * ATILE_);
#pragma unroll
        for (int r = 0; r < 4; r++)
            async16(gA + (size_t)r * 64 * K + k0, lp + r * 8192 + tid * 16);
    };
    auto stageB = [&](int buf, int k0) {
        char* lp = (char*)(Bs0 + buf * ATILE_);
#pragma unroll
        for (int r = 0; r < 4; r++)
            async16(gB + (size_t)r * 64 * K + k0, lp + r * 8192 + tid * 16);
    };

    v4f acc[8][4];
#pragma unroll
    for (int i = 0; i < 8; i++)
#pragma unroll
        for (int j = 0; j < 4; j++) acc[i][j] = (v4f){0.f, 0.f, 0.f, 0.f};

    float bj[4];
#pragma unroll
    for (int jj = 0; jj < 4; jj++) bj[jj] = bias[col0 + wc * 64 + jj * 16 + lm];

    v8s aLo[4][2], aHi[4][2], bF[4][2];

    auto RD_A = [&](const short* base, int half, v8s (*dst)[2]) {
#pragma unroll
        for (int i = 0; i < 4; i++) {
            const int m = wr * 128 + half * 64 + i * 16 + lm;
#pragma unroll
            for (int ks = 0; ks < 2; ks++)
                dst[i][ks] = *(const v8s*)(base + m * 64 + (((ks << 2) | g) ^ (m & 7)) * 8);
        }
    };
    auto RD_B = [&](const short* base) {
#pragma unroll
        for (int j = 0; j < 4; j++) {
            const int n = wc * 64 + j * 16 + lm;
#pragma unroll
            for (int ks = 0; ks < 2; ks++)
                bF[j][ks] = *(const v8s*)(base + n * 64 + (((ks << 2) | g) ^ (n & 7)) * 8);
        }
    };
    auto MFMA_H = [&](int half, v8s (*af)[2]) {
        __builtin_amdgcn_s_setprio(1);
#pragma unroll
        for (int i = 0; i < 4; i++)
#pragma unroll
            for (int j = 0; j < 4; j++) {
                acc[half*4+i][j] = __builtin_amdgcn_mfma_f32_16x16x32_bf16(af[i][0], bF[j][0], acc[half*4+i][j], 0, 0, 0);
                acc[half*4+i][j] = __builtin_amdgcn_mfma_f32_16x16x32_bf16(af[i][1], bF[j][1], acc[half*4+i][j], 0, 0, 0);
            }
        __builtin_amdgcn_s_setprio(0);
    };

    stageB(0, 0); stageA(0, 0);
    stageB(1, 64); stageA(1, 64);
    asm volatile("s_waitcnt vmcnt(8)" ::: "memory");
    __builtin_amdgcn_s_barrier();
    asm volatile("" ::: "memory");

    for (int T = 0; T < NT; ++T) {
        const int cur = T & 1;
        const short* as = As0 + cur * ATILE_;
        const short* bs = Bs0 + cur * ATILE_;
        const bool s2 = (T + 2 < NT);
        const int k2 = (T + 2) << 6;

        RD_B(bs);
        RD_A(as, 0, aLo);
        asm volatile("s_waitcnt lgkmcnt(0)" ::: "memory");
        __builtin_amdgcn_s_barrier();       // Bs[cur] fully read everywhere
        if (s2) stageB(cur, k2);
        MFMA_H(0, aLo);
        RD_A(as, 1, aHi);                    // As[cur]; disjoint from stageB
        asm volatile("s_waitcnt lgkmcnt(0)" ::: "memory");
        __builtin_amdgcn_s_barrier();       // As[cur] fully read everywhere
        if (s2) stageA(cur, k2);
        MFMA_H(1, aHi);
        if (s2)              asm volatile("s_waitcnt vmcnt(8)" ::: "memory");
        else if (T + 1 < NT) asm volatile("s_waitcnt vmcnt(0)" ::: "memory");
        __builtin_amdgcn_s_barrier();
        asm volatile("" ::: "memory");
    }

    float* ep = (float*)smem + w * (16 * 68);
#pragma unroll
    for (int ii = 0; ii < 8; ii++) {
#pragma unroll
        for (int jj = 0; jj < 4; jj++)
#pragma unroll
            for (int r = 0; r < 4; r++)
                ep[(g * 4 + r) * 68 + jj * 16 + lm] = acc[ii][jj][r] + bj[jj];
        asm volatile("s_waitcnt lgkmcnt(0)" ::: "memory");
        const int rr = lane >> 2, cb = (lane & 3) * 16;
        float4 f0 = *(float4*)(ep + rr * 68 + cb + 0);
        float4 f1 = *(float4*)(ep + rr * 68 + cb + 4);
        float4 f2 = *(float4*)(ep + rr * 68 + cb + 8);
        float4 f3 = *(float4*)(ep + rr * 68 + cb + 12);
        asm volatile("s_waitcnt lgkmcnt(0)" ::: "memory");
        const int grow = row0 + wr * 128 + ii * 16 + rr;
        const int gcol = col0 + wc * 64 + cb;
        storeRow(&C[(size_t)grow * N + gcol], f0, f1, f2, f3);
    }
}

// output projection GEMM (old structure; 256 blocks, small)
__global__ __launch_bounds__(256) void gemm_out(
    const short* __restrict__ A, const short* __restrict__ Bt,
    const float* __restrict__ bias, float* __restrict__ C) {
    __shared__ short smem[2 * 128 * 64];
    const int lin = blockIdx.y * gridDim.x + blockIdx.x;
    gemm_body<float>(smem, A, Bt, bias, C, 256, 512, 2, lin);
}

// ---------------------------------------------------------------------------
// Attention: 16-lane groups, 4 samples/wave. Lane owns 4-elem DH slice.
// kvproj layout [row][1024]: k cols 0-511, v 512+. q pre-scaled by 0.125.
// ---------------------------------------------------------------------------
__global__ __launch_bounds__(256) void attn_kernel(
    const short* __restrict__ qb, const short* __restrict__ kvproj,
    const int* __restrict__ idx, short* __restrict__ attnout) {
    const int lane = threadIdx.x & 63;
    const int wv   = threadIdx.x >> 6;
    const int s    = lane >> 4, c = lane & 15;
    const int n = blockIdx.x * 16 + wv * 4 + s;
    const int h = blockIdx.y, b = blockIdx.z;
    const int m = b * N_ + n;

    v4s qv = *(const v4s*)(qb + (size_t)m * INNER_ + h * DH_ + c * 4);

    const int* ip = idx + ((size_t)(b * H_ + h) * N_ + n) * P_;
    int j0 = ip[0], j1 = ip[1];
    int r0 = b * N_ + j0 + ((j0 >= N_) ? (BN_ - N_) : 0);
    int r1 = b * N_ + j1 + ((j1 >= N_) ? (BN_ - N_) : 0);
    const short* k0p = kvproj + (size_t)r0 * 1024 + h * DH_ + c * 4;
    const short* k1p = kvproj + (size_t)r1 * 1024 + h * DH_ + c * 4;
    v4s k0 = *(const v4s*)k0p, v0 = *(const v4s*)(k0p + 512);
    v4s k1 = *(const v4s*)k1p, v1 = *(const v4s*)(k1p + 512);

    float q0 = b2f(qv[0]), q1 = b2f(qv[1]), q2 = b2f(qv[2]), q3 = b2f(qv[3]);
    float s0 = q0 * b2f(k0[0]) + q1 * b2f(k0[1]) + q2 * b2f(k0[2]) + q3 * b2f(k0[3]);
    float s1 = q0 * b2f(k1[0]) + q1 * b2f(k1[1]) + q2 * b2f(k1[2]) + q3 * b2f(k1[3]);
#pragma unroll
    for (int d = 1; d <= 8; d <<= 1) {
        s0 += __shfl_xor(s0, d);
        s1 += __shfl_xor(s1, d);
    }
    float mx = fmaxf(s0, s1);
    float e0 = __expf(s0 - mx), e1 = __expf(s1 - mx);
    float inv = 1.f / (e0 + e1);
    v4s o;
#pragma unroll
    for (int i = 0; i < 4; i++)
        o[i] = f2b((e0 * b2f(v0[i]) + e1 * b2f(v1[i])) * inv);
    *(v4s*)(attnout + (size_t)m * INNER_ + h * DH_ + c * 4) = o;
}

// ---------------------------------------------------------------------------
extern "C" void kernel_launch(void* const* d_in, const int* in_sizes, int n_in,
                              void* d_out, int out_size, void* d_ws, size_t ws_size,
                              hipStream_t stream) {
    (void)in_sizes; (void)n_in; (void)out_size; (void)ws_size;

    const float* x      = (const float*)d_in[0];
    const float* prevx  = (const float*)d_in[1];
    const float* ln_q_g = (const float*)d_in[2];
    const float* ln_q_b = (const float*)d_in[3];
    const float* ln_k_g = (const float*)d_in[4];
    const float* ln_k_b = (const float*)d_in[5];
    const float* ln_v_g = (const float*)d_in[6];
    const float* ln_v_b = (const float*)d_in[7];
    const float* Wq     = (const float*)d_in[8];
    const float* Wk     = (const float*)d_in[9];
    const float* bk     = (const float*)d_in[10];
    const float* Wv     = (const float*)d_in[11];
    const float* bv     = (const float*)d_in[12];
    const float* Woff   = (const float*)d_in[13];
    const float* boff   = (const float*)d_in[14];
    const float* Wout   = (const float*)d_in[15];
    const float* bout   = (const float*)d_in[16];

    char* cur = (char*)d_ws;
    auto alloc = [&](size_t bytes) { char* p = cur; cur += (bytes + 255) & ~(size_t)255; return p; };
    short* Aq      = (short*)alloc((size_t)BN_ * INNER_ * 2);     // 16 MB
    short* Akv     = (short*)alloc((size_t)KVR_ * DIM_ * 2);      // 16 MB
    short* qb      = (short*)alloc((size_t)BN_ * INNER_ * 2);     // 16 MB
    short* kvproj  = (short*)alloc((size_t)KVR_ * 1024 * 2);      // 64 MB
    short* attnout = (short*)alloc((size_t)BN_ * INNER_ * 2);     // 16 MB
    short* Wq2t    = (short*)alloc(512 * 512 * 2);
    short* Wkvt    = (short*)alloc(1024 * 256 * 2);
    short* Woutb   = (short*)alloc(256 * 512 * 2);
    float* bq2     = (float*)alloc(512 * 4);
    float* bkv     = (float*)alloc(1024 * 4);
    float* Wcomb   = (float*)alloc(512 * 16 * 4);
    float* braw    = (float*)alloc(512 * 16 * 4);
    float* bcomb   = (float*)alloc(16 * 4);
    int*   idxb    = (int*)alloc((size_t)BN_ * 16 * 4);
    // total ~130 MB

    float* out_main = (float*)d_out;                      // (B,N,DIM)
    float* out_off  = out_main + (size_t)BN_ * DIM_;      // (B,H,P,N)

    // 1) merged weight prep + composed offset weights
    prep_all<<<2176, 256, 0, stream>>>(Wq, ln_q_g, ln_q_b,
                                       Wk, ln_k_g, ln_k_b, bk,
                                       Wv, ln_v_g, ln_v_b, bv,
                                       Woff, Wout,
                                       Wq2t, bq2, Wkvt, bkv, Wcomb, braw, Woutb);
    bcomb_sum<<<1, 256, 0, stream>>>(braw, boff, bcomb);

    // 2) fused LN + activations + offsets + indices (R7 internals)
    norm_fused_kernel<<<BN_ / 16, 256, 0, stream>>>(x, prevx, Wcomb, bcomb,
                                                    Aq, Akv, out_off, idxb);

    // 3) q + kv projections: R3's 256^2 3-barrier schedule
    gemm_qkv_256<<<640, 512, 0, stream>>>(Aq, Wq2t, bq2, (__hip_bfloat16*)qb,
                                          Akv, Wkvt, bkv, (__hip_bfloat16*)kvproj);

    // 4) gather + softmax(P=2) + weighted sum
    dim3 ga(N_ / 16, H_, B_);
    attn_kernel<<<ga, 256, 0, stream>>>(qb, kvproj, idxb, attnout);

    // 5) output projection
    gemm_out<<<dim3(2, 128), 256, 0, stream>>>(attnout, Woutb, bout, out_main);
}